// Round 14
// baseline (6721.271 us; speedup 1.0000x reference)
//
#include <hip/hip_runtime.h>
#include <math.h>

#define BB 16
#define TT 16
#define EE 128
#define KS 15
#define MM 41
#define OO 4
#define VR 7
#define SS 27
#define NSTEP 15
#define PP (MM*MM)
#define NROWS (BB*PP)

#define RAWS_OFF 0
#define SPS_OFF  1613760
#define MAPS_OFF 3227520

#define PM 55
#define PMSZ (PM*PM)
#define NPS 3

typedef __attribute__((ext_vector_type(8))) short short8v;
typedef __attribute__((ext_vector_type(4))) float f32x4;
typedef __attribute__((ext_vector_type(2))) __bf16 bf16x2;
typedef unsigned short ushort;
typedef unsigned int uint;

__device__ __forceinline__ float sigf(float x) { return 1.f / (1.f + expf(-x)); }

__device__ __forceinline__ ushort f2bf(float x) {
    unsigned int u = __float_as_uint(x);
    u += 0x7FFF + ((u >> 16) & 1);
    return (ushort)(u >> 16);
}
__device__ __forceinline__ float bf2f(ushort u) {
    return __uint_as_float((unsigned int)u << 16);
}

__device__ __forceinline__ int rotoff(int o, int r, int c) {
    int ir, ic;
    if (o == 0)      { ir = r;      ic = c;      }
    else if (o == 1) { ir = c;      ic = 14 - r; }
    else if (o == 2) { ir = 14 - r; ic = 14 - c; }
    else             { ir = 14 - c; ic = r;      }
    return ir * 15 + ic;
}

__global__ void k_init(float* __restrict__ pose) {
    int idx = blockIdx.x * 256 + threadIdx.x;
    if (idx < BB * OO * MM * MM) {
        int r = idx % (OO * MM * MM);
        pose[idx] = (r == (20 * MM + 20)) ? 1.f : 0.f;
    }
}

// Wt[jp][k] bf16 (B^T layout for MFMA), jp = jj*4+g; bc[jp] = bih+bhh
__global__ void k_prep(const float* __restrict__ wih, const float* __restrict__ whh,
                       const float* __restrict__ bih, const float* __restrict__ bhh,
                       ushort* __restrict__ Wt, float* __restrict__ bc) {
    int idx = blockIdx.x * 256 + threadIdx.x;   // [0, 512*256)
    int jp = idx >> 8, k = idx & 255;
    int jj = jp >> 2, g = jp & 3, j = g * 128 + jj;
    float v = (k < 128) ? wih[j * 128 + k] : whh[j * 128 + (k - 128)];
    Wt[(size_t)jp * 256 + k] = f2bf(v);
    if (idx < 512) {
        int jj2 = idx >> 2, g2 = idx & 3, j2 = g2 * 128 + jj2;
        bc[idx] = bih[j2] + bhh[j2];
    }
}

// register conv-transpose (R4-verified index math); bf16 output.
__global__ __launch_bounds__(256) void k_register(const float* __restrict__ images,
                                                  const float* __restrict__ pose,
                                                  ushort* __restrict__ reg16, int t) {
    __shared__ float ps[OO * PMSZ];
    __shared__ float wsm[225][36];
    const int p0 = blockIdx.x * 256;
    const int eq = blockIdx.y;
    const int b  = blockIdx.z;
    const int tid = threadIdx.x;

    for (int i = tid; i < OO * PMSZ; i += 256) {
        int o = i / PMSZ, rem = i % PMSZ, r = rem / PM, c = rem % PM;
        float v = 0.f;
        if (r >= VR && r < VR + MM && c >= VR && c < VR + MM)
            v = pose[(((size_t)b * OO + o) * MM + (r - VR)) * MM + (c - VR)];
        ps[i] = v;
    }
    const float* img = images + ((size_t)(b * TT + t) * EE + eq * 32) * 225;
    for (int i = tid; i < 32 * 225; i += 256) {
        int e = i / 225, k = i - e * 225;
        wsm[k][e] = img[e * 225 + k];
    }
    __syncthreads();

    const int px = tid & 63;
    const int ec = tid >> 6;
    int pbase[4];
    #pragma unroll
    for (int i = 0; i < 4; ++i) {
        int p = p0 + px + 64 * i;
        int pc = (p < PP) ? p : 0;
        int y = pc / MM, x = pc - y * MM;
        pbase[i] = (y + 2 * VR) * PM + (x + 2 * VR);
    }

    float acc[4][8];
    #pragma unroll
    for (int i = 0; i < 4; ++i)
        #pragma unroll
        for (int j = 0; j < 8; ++j) acc[i][j] = 0.f;

    for (int R = 0; R < 15; ++R) {
        #pragma unroll 5
        for (int C = 0; C < 15; ++C) {
            float4 wv0 = *(const float4*)&wsm[R * 15 + C][ec * 8];
            float4 wv1 = *(const float4*)&wsm[R * 15 + C][ec * 8 + 4];
            #pragma unroll
            for (int i = 0; i < 4; ++i) {
                float a0 = ps[0 * PMSZ + pbase[i] - R * PM - C];
                float a1 = ps[1 * PMSZ + pbase[i] + (C - 14) * PM - R];
                float a2 = ps[2 * PMSZ + pbase[i] + (R - 14) * PM + (C - 14)];
                float a3 = ps[3 * PMSZ + pbase[i] - C * PM + (R - 14)];
                float s = (a0 + a1) + (a2 + a3);
                acc[i][0] += s * wv0.x; acc[i][1] += s * wv0.y;
                acc[i][2] += s * wv0.z; acc[i][3] += s * wv0.w;
                acc[i][4] += s * wv1.x; acc[i][5] += s * wv1.y;
                acc[i][6] += s * wv1.z; acc[i][7] += s * wv1.w;
            }
        }
    }

    #pragma unroll
    for (int i = 0; i < 4; ++i) {
        int p = p0 + px + 64 * i;
        if (p < PP) {
            ushort* dst = reg16 + ((size_t)b * PP + p) * EE + eq * 32 + ec * 8;
            ushort u[8];
            #pragma unroll
            for (int j = 0; j < 8; ++j) u[j] = f2bf(acc[i][j]);
            *(uint4*)dst = *(uint4*)u;
        }
    }
}

// LSTM: bf16 MFMA GEMM (64n x 64jp block, 2x2 waves of 32x32) + fp32 epilogue
// + fused transposed maps write. A = [reg16 | hb16in], B^T = Wt.
__global__ __launch_bounds__(256) void k_lstm(const ushort* __restrict__ reg16,
                                              const ushort* __restrict__ hb16in,
                                              const ushort* __restrict__ Wt,
                                              const float* __restrict__ bc,
                                              ushort* __restrict__ hb16out,
                                              float* __restrict__ cst,
                                              float* __restrict__ out, int t) {
    __shared__ float gsm[64][68];
    __shared__ float h2sm[64][17];
    const int tid = threadIdx.x;
    const int wave = tid >> 6, lane = tid & 63;
    const int wm = wave >> 1, wn = wave & 1;
    const int n0 = blockIdx.x * 64;
    const int jp0 = blockIdx.y * 64;
    const int lr = lane & 15;
    const int lk = (lane >> 4) * 8;

    f32x4 acc[2][2];
    #pragma unroll
    for (int fm = 0; fm < 2; ++fm)
        #pragma unroll
        for (int fn = 0; fn < 2; ++fn) acc[fm][fn] = (f32x4){0.f, 0.f, 0.f, 0.f};

    size_t aoff[2];
    #pragma unroll
    for (int fm = 0; fm < 2; ++fm) {
        int n = n0 + wm * 32 + fm * 16 + lr;
        aoff[fm] = (size_t)((n < NROWS) ? n : (NROWS - 1)) * EE;
    }
    size_t boff[2];
    #pragma unroll
    for (int fn = 0; fn < 2; ++fn)
        boff[fn] = (size_t)(jp0 + wn * 32 + fn * 16 + lr) * 256;

    #pragma unroll
    for (int ks = 0; ks < 8; ++ks) {
        const ushort* src = (ks < 4) ? reg16 : hb16in;
        const int koff = ((ks < 4) ? ks : (ks - 4)) * 32 + lk;
        short8v a0 = *(const short8v*)(src + aoff[0] + koff);
        short8v a1 = *(const short8v*)(src + aoff[1] + koff);
        short8v b0 = *(const short8v*)(Wt + boff[0] + ks * 32 + lk);
        short8v b1 = *(const short8v*)(Wt + boff[1] + ks * 32 + lk);
        acc[0][0] = __builtin_amdgcn_mfma_f32_16x16x32_bf16(a0, b0, acc[0][0], 0, 0, 0);
        acc[0][1] = __builtin_amdgcn_mfma_f32_16x16x32_bf16(a0, b1, acc[0][1], 0, 0, 0);
        acc[1][0] = __builtin_amdgcn_mfma_f32_16x16x32_bf16(a1, b0, acc[1][0], 0, 0, 0);
        acc[1][1] = __builtin_amdgcn_mfma_f32_16x16x32_bf16(a1, b1, acc[1][1], 0, 0, 0);
    }

    #pragma unroll
    for (int fm = 0; fm < 2; ++fm)
        #pragma unroll
        for (int fn = 0; fn < 2; ++fn)
            #pragma unroll
            for (int r = 0; r < 4; ++r)
                gsm[wm * 32 + fm * 16 + (lane >> 4) * 4 + r]
                   [wn * 32 + fn * 16 + (lane & 15)] = acc[fm][fn][r];
    __syncthreads();

    const int jjl = tid & 15;
    const int jj = (jp0 >> 2) + jjl;
    const float4 bv = *(const float4*)(bc + jp0 + jjl * 4);
    #pragma unroll
    for (int i = 0; i < 4; ++i) {
        int nrel = (tid >> 4) * 4 + i;
        int n = n0 + nrel;
        float4 g = *(const float4*)&gsm[nrel][jjl * 4];
        float h2 = 0.f;
        if (n < NROWS) {
            float gi = g.x + bv.x, gf = g.y + bv.y, gg = g.z + bv.z, go = g.w + bv.w;
            size_t off = (size_t)n * EE + jj;
            float cv = cst[off];
            float c2 = sigf(gf) * cv + sigf(gi) * tanhf(gg);
            h2 = sigf(go) * tanhf(c2);
            cst[off] = c2;
            hb16out[off] = f2bf(h2);
        }
        h2sm[nrel][jjl] = h2;
    }
    __syncthreads();

    const int nrel2 = tid & 63;
    const int n2 = n0 + nrel2;
    if (n2 < NROWS) {
        const int b2 = n2 / PP, p2 = n2 - b2 * PP;
        const size_t base = MAPS_OFF + ((size_t)(b2 * NSTEP + t) * EE) * PP + p2;
        #pragma unroll
        for (int pass = 0; pass < 4; ++pass) {
            int jl = pass * 4 + (tid >> 6);
            out[base + (size_t)((jp0 >> 2) + jl) * PP] = h2sm[nrel2][jl];
        }
    }
}

// wprep: wT16[b][o][tap][e] = bf16( rot_o(img[b,t+1])[e][tap] )
__global__ __launch_bounds__(256) void k_wprep(const float* __restrict__ images,
                                               ushort* __restrict__ wT16, int t) {
    __shared__ float img_s[64][225];
    const int eh = blockIdx.x;
    const int o  = blockIdx.y;
    const int b  = blockIdx.z;
    const int tid = threadIdx.x;
    const float* img = images + ((size_t)(b * TT + t + 1) * EE + eh * 64) * 225;
    for (int i = tid; i < 64 * 225; i += 256)
        img_s[i / 225][i % 225] = img[i];
    __syncthreads();
    ushort* w = wT16 + ((size_t)(b * OO + o) * 225) * EE + eh * 64;
    for (int j = tid; j < 225 * 64; j += 256) {
        int tap = j >> 6, el = j & 63;
        int r = tap / 15, c = tap - r * 15;
        w[(size_t)tap * EE + el] = f2bf(img_s[el][rotoff(o, r, c)]);
    }
}

// localize v8: dy split into GRID thirds (5 dys each) -> LDS slab is only
// 5 rows x 41 x 128 bf16 = 52.5 KB -> 3 blocks/CU (3 waves/SIMD, was 1/2).
// Block = (y, b, dyt); 256 thr = 4 waves = o; lane = e-pair, packed dot2
// (v7-proven no-spill shape). Staging bytes unchanged (thirds are disjoint).
// rawp: [dyt=3][b][o][729] partials.
__global__ __launch_bounds__(256, 3) void k_localize(const ushort* __restrict__ h16,
                                                     const ushort* __restrict__ wT16,
                                                     float* __restrict__ rawp) {
    __shared__ ushort tile[5 * MM * EE];   // 52,480 B
    const int y   = blockIdx.x;            // 0..26
    const int b   = blockIdx.y;
    const int dyt = blockIdx.z;            // 0..2
    const int tid = threadIdx.x;
    const int o    = tid >> 6;             // wave = orientation
    const int lane = tid & 63;             // e-pair index
    const int dy0 = dyt * 5;

    // stage rows [y+dy0, y+dy0+5) x 128 e (contiguous, coalesced)
    const uint4* s4 = (const uint4*)(h16 + ((size_t)b * PP + (size_t)(y + dy0) * MM) * EE);
    uint4* d4 = (uint4*)tile;
    for (int i = tid; i < 3280; i += 256) d4[i] = s4[i];
    __syncthreads();

    float acc[SS];
    #pragma unroll
    for (int x = 0; x < SS; ++x) acc[x] = 0.f;

    const uint* tl = (const uint*)tile + lane;
    const uint* wo = (const uint*)(wT16 + (((size_t)b * OO + o) * 225) * EE) + lane;

    #pragma unroll
    for (int dyl = 0; dyl < 5; ++dyl) {
        uint hrow[MM];
        const uint* tr = tl + (size_t)dyl * MM * 64;
        #pragma unroll
        for (int c = 0; c < MM; ++c) hrow[c] = tr[c * 64];
        const uint* wd = wo + (size_t)((dy0 + dyl) * 15) * 64;
        #pragma unroll
        for (int dx = 0; dx < 15; ++dx) {
            uint uw = wd[dx * 64];
#if __has_builtin(__builtin_amdgcn_fdot2_f32_bf16)
            bf16x2 w2 = __builtin_bit_cast(bf16x2, uw);
            #pragma unroll
            for (int x = 0; x < SS; ++x)
                acc[x] = __builtin_amdgcn_fdot2_f32_bf16(
                    __builtin_bit_cast(bf16x2, hrow[x + dx]), w2, acc[x], false);
#else
            float wl = bf2f((ushort)(uw & 0xffffu));
            float wh = bf2f((ushort)(uw >> 16));
            #pragma unroll
            for (int x = 0; x < SS; ++x) {
                uint hu = hrow[x + dx];
                acc[x] += bf2f((ushort)(hu & 0xffffu)) * wl
                        + bf2f((ushort)(hu >> 16)) * wh;
            }
#endif
        }
    }

    #pragma unroll
    for (int x = 0; x < SS; ++x) {
        float v = acc[x];
        v += __shfl_xor(v, 1);  v += __shfl_xor(v, 2);  v += __shfl_xor(v, 4);
        v += __shfl_xor(v, 8);  v += __shfl_xor(v, 16); v += __shfl_xor(v, 32);
        if (lane == 0)
            rawp[(((size_t)dyt * BB + b) * OO + o) * (SS * SS) + y * SS + x] = v;
    }
}

__global__ __launch_bounds__(256) void k_softmax(const float* __restrict__ rawp,
                                                 float* __restrict__ out,
                                                 float* __restrict__ pose, int t) {
    const int b = blockIdx.x, tid = threadIdx.x;
    const int NTOT = OO * SS * SS;
    __shared__ float sv[OO * SS * SS];
    __shared__ float red[256];

    const float* p0 = rawp + (size_t)b * NTOT;
    for (int i = tid; i < NTOT; i += 256) {
        float s = 0.f;
        #pragma unroll
        for (int q = 0; q < NPS; ++q) s += p0[(size_t)q * BB * NTOT + i];
        sv[i] = s;
    }
    __syncthreads();

    float mx = -3.4e38f;
    for (int i = tid; i < NTOT; i += 256) mx = fmaxf(mx, sv[i]);
    red[tid] = mx; __syncthreads();
    for (int s = 128; s > 0; s >>= 1) {
        if (tid < s) red[tid] = fmaxf(red[tid], red[tid + s]);
        __syncthreads();
    }
    mx = red[0]; __syncthreads();

    float sm = 0.f;
    for (int i = tid; i < NTOT; i += 256) sm += expf(sv[i] - mx);
    red[tid] = sm; __syncthreads();
    for (int s = 128; s > 0; s >>= 1) {
        if (tid < s) red[tid] += red[tid + s];
        __syncthreads();
    }
    const float inv = 1.f / red[0];

    float* rawOut = out + RAWS_OFF + ((size_t)(b * NSTEP + t) * OO) * PP;
    float* spOut  = out + SPS_OFF  + ((size_t)(b * NSTEP + t) * OO) * PP;
    float* pb = pose + (size_t)b * OO * MM * MM;
    for (int i = tid; i < OO * MM * MM; i += 256) {
        int o = i / (MM * MM), rem = i % (MM * MM), yy = rem / MM - VR, xx = rem % MM - VR;
        float rv = 0.f, sv2 = 0.f;
        if ((unsigned)yy < SS && (unsigned)xx < SS) {
            float r = sv[(o * SS + yy) * SS + xx];
            rv = r;
            sv2 = expf(r - mx) * inv;
        }
        rawOut[i] = rv;
        spOut[i] = sv2;
        pb[i] = sv2;
    }
}

extern "C" void kernel_launch(void* const* d_in, const int* in_sizes, int n_in,
                              void* d_out, int out_size, void* d_ws, size_t ws_size,
                              hipStream_t stream) {
    const float* images = (const float*)d_in[0];
    const float* wih    = (const float*)d_in[1];
    const float* whh    = (const float*)d_in[2];
    const float* bih    = (const float*)d_in[3];
    const float* bhh    = (const float*)d_in[4];
    float* out = (float*)d_out;
    float* ws  = (float*)d_ws;

    // layout (float units), total ~10.5M floats = 42 MB
    float*  pose  = ws;                                   // 107,584
    float*  cst   = pose + 107584;                        // 3,442,688 fp32
    ushort* hbA   = (ushort*)(cst + 3442688);             // 1,721,344 float-slots
    ushort* hbB   = (ushort*)(cst + 3442688 + 1721344);   // 1,721,344 float-slots
    float*  regbF = cst + 3442688 + 2 * 1721344;          // 3,442,688 region
    ushort* reg16 = (ushort*)regbF;                       // bf16 reg
    // aliases inside regb region (dead between k_lstm(t) and k_register(t+1)):
    float*  rawp  = regbF;                                // 139,968 floats (NPS=3)
    ushort* wT16  = (ushort*)(regbF + 262144);            // 921,600 float-slots
    ushort* Wt    = (ushort*)(regbF + 3442688);           // 65,536 float-slots
    float*  bc    = regbF + 3442688 + 65536;              // 512

    hipMemsetAsync(hbA, 0, (size_t)1721344 * 4, stream);
    hipMemsetAsync(cst, 0, (size_t)3442688 * 4, stream);
    k_init<<<421, 256, 0, stream>>>(pose);
    k_prep<<<512, 256, 0, stream>>>(wih, whh, bih, bhh, Wt, bc);

    ushort* hbin = hbA;
    ushort* hbout = hbB;
    for (int t = 0; t < NSTEP; ++t) {
        k_register<<<dim3(7, 4, BB), 256, 0, stream>>>(images, pose, reg16, t);
        k_lstm<<<dim3(421, 8), 256, 0, stream>>>(reg16, hbin, Wt, bc, hbout, cst, out, t);
        k_wprep<<<dim3(2, OO, BB), 256, 0, stream>>>(images, wT16, t);
        k_localize<<<dim3(SS, BB, 3), 256, 0, stream>>>(hbout, wT16, rawp);
        k_softmax<<<BB, 256, 0, stream>>>(rawp, out, pose, t);
        ushort* tmp = hbin; hbin = hbout; hbout = tmp;
    }
}

// Round 15
// 2899.431 us; speedup vs baseline: 2.3181x; 2.3181x over previous
//
#include <hip/hip_runtime.h>
#include <math.h>

#define BB 16
#define TT 16
#define EE 128
#define KS 15
#define MM 41
#define OO 4
#define VR 7
#define SS 27
#define NSTEP 15
#define PP (MM*MM)
#define NROWS (BB*PP)

#define RAWS_OFF 0
#define SPS_OFF  1613760
#define MAPS_OFF 3227520

#define PM 55
#define PMSZ (PM*PM)
#define NPS 3

typedef __attribute__((ext_vector_type(8))) short short8v;
typedef __attribute__((ext_vector_type(4))) float f32x4;
typedef __attribute__((ext_vector_type(2))) __bf16 bf16x2;
typedef unsigned short ushort;
typedef unsigned int uint;

__device__ __forceinline__ float sigf(float x) { return 1.f / (1.f + expf(-x)); }

__device__ __forceinline__ ushort f2bf(float x) {
    unsigned int u = __float_as_uint(x);
    u += 0x7FFF + ((u >> 16) & 1);
    return (ushort)(u >> 16);
}
__device__ __forceinline__ float bf2f(ushort u) {
    return __uint_as_float((unsigned int)u << 16);
}

__device__ __forceinline__ int rotoff(int o, int r, int c) {
    int ir, ic;
    if (o == 0)      { ir = r;      ic = c;      }
    else if (o == 1) { ir = c;      ic = 14 - r; }
    else if (o == 2) { ir = 14 - r; ic = 14 - c; }
    else             { ir = 14 - c; ic = r;      }
    return ir * 15 + ic;
}

__global__ void k_init(float* __restrict__ pose) {
    int idx = blockIdx.x * 256 + threadIdx.x;
    if (idx < BB * OO * MM * MM) {
        int r = idx % (OO * MM * MM);
        pose[idx] = (r == (20 * MM + 20)) ? 1.f : 0.f;
    }
}

// Wt[jp][k] bf16 (B^T layout for MFMA), jp = jj*4+g; bc[jp] = bih+bhh
__global__ void k_prep(const float* __restrict__ wih, const float* __restrict__ whh,
                       const float* __restrict__ bih, const float* __restrict__ bhh,
                       ushort* __restrict__ Wt, float* __restrict__ bc) {
    int idx = blockIdx.x * 256 + threadIdx.x;   // [0, 512*256)
    int jp = idx >> 8, k = idx & 255;
    int jj = jp >> 2, g = jp & 3, j = g * 128 + jj;
    float v = (k < 128) ? wih[j * 128 + k] : whh[j * 128 + (k - 128)];
    Wt[(size_t)jp * 256 + k] = f2bf(v);
    if (idx < 512) {
        int jj2 = idx >> 2, g2 = idx & 3, j2 = g2 * 128 + jj2;
        bc[idx] = bih[j2] + bhh[j2];
    }
}

// register conv-transpose (R4-verified index math); bf16 output.
__global__ __launch_bounds__(256) void k_register(const float* __restrict__ images,
                                                  const float* __restrict__ pose,
                                                  ushort* __restrict__ reg16, int t) {
    __shared__ float ps[OO * PMSZ];
    __shared__ float wsm[225][36];
    const int p0 = blockIdx.x * 256;
    const int eq = blockIdx.y;
    const int b  = blockIdx.z;
    const int tid = threadIdx.x;

    for (int i = tid; i < OO * PMSZ; i += 256) {
        int o = i / PMSZ, rem = i % PMSZ, r = rem / PM, c = rem % PM;
        float v = 0.f;
        if (r >= VR && r < VR + MM && c >= VR && c < VR + MM)
            v = pose[(((size_t)b * OO + o) * MM + (r - VR)) * MM + (c - VR)];
        ps[i] = v;
    }
    const float* img = images + ((size_t)(b * TT + t) * EE + eq * 32) * 225;
    for (int i = tid; i < 32 * 225; i += 256) {
        int e = i / 225, k = i - e * 225;
        wsm[k][e] = img[e * 225 + k];
    }
    __syncthreads();

    const int px = tid & 63;
    const int ec = tid >> 6;
    int pbase[4];
    #pragma unroll
    for (int i = 0; i < 4; ++i) {
        int p = p0 + px + 64 * i;
        int pc = (p < PP) ? p : 0;
        int y = pc / MM, x = pc - y * MM;
        pbase[i] = (y + 2 * VR) * PM + (x + 2 * VR);
    }

    float acc[4][8];
    #pragma unroll
    for (int i = 0; i < 4; ++i)
        #pragma unroll
        for (int j = 0; j < 8; ++j) acc[i][j] = 0.f;

    for (int R = 0; R < 15; ++R) {
        #pragma unroll 5
        for (int C = 0; C < 15; ++C) {
            float4 wv0 = *(const float4*)&wsm[R * 15 + C][ec * 8];
            float4 wv1 = *(const float4*)&wsm[R * 15 + C][ec * 8 + 4];
            #pragma unroll
            for (int i = 0; i < 4; ++i) {
                float a0 = ps[0 * PMSZ + pbase[i] - R * PM - C];
                float a1 = ps[1 * PMSZ + pbase[i] + (C - 14) * PM - R];
                float a2 = ps[2 * PMSZ + pbase[i] + (R - 14) * PM + (C - 14)];
                float a3 = ps[3 * PMSZ + pbase[i] - C * PM + (R - 14)];
                float s = (a0 + a1) + (a2 + a3);
                acc[i][0] += s * wv0.x; acc[i][1] += s * wv0.y;
                acc[i][2] += s * wv0.z; acc[i][3] += s * wv0.w;
                acc[i][4] += s * wv1.x; acc[i][5] += s * wv1.y;
                acc[i][6] += s * wv1.z; acc[i][7] += s * wv1.w;
            }
        }
    }

    #pragma unroll
    for (int i = 0; i < 4; ++i) {
        int p = p0 + px + 64 * i;
        if (p < PP) {
            ushort* dst = reg16 + ((size_t)b * PP + p) * EE + eq * 32 + ec * 8;
            ushort u[8];
            #pragma unroll
            for (int j = 0; j < 8; ++j) u[j] = f2bf(acc[i][j]);
            *(uint4*)dst = *(uint4*)u;
        }
    }
}

// LSTM: bf16 MFMA GEMM (64n x 64jp block, 2x2 waves of 32x32) + fp32 epilogue
// + fused transposed maps write. A = [reg16 | hb16in], B^T = Wt.
__global__ __launch_bounds__(256) void k_lstm(const ushort* __restrict__ reg16,
                                              const ushort* __restrict__ hb16in,
                                              const ushort* __restrict__ Wt,
                                              const float* __restrict__ bc,
                                              ushort* __restrict__ hb16out,
                                              float* __restrict__ cst,
                                              float* __restrict__ out, int t) {
    __shared__ float gsm[64][68];
    __shared__ float h2sm[64][17];
    const int tid = threadIdx.x;
    const int wave = tid >> 6, lane = tid & 63;
    const int wm = wave >> 1, wn = wave & 1;
    const int n0 = blockIdx.x * 64;
    const int jp0 = blockIdx.y * 64;
    const int lr = lane & 15;
    const int lk = (lane >> 4) * 8;

    f32x4 acc[2][2];
    #pragma unroll
    for (int fm = 0; fm < 2; ++fm)
        #pragma unroll
        for (int fn = 0; fn < 2; ++fn) acc[fm][fn] = (f32x4){0.f, 0.f, 0.f, 0.f};

    size_t aoff[2];
    #pragma unroll
    for (int fm = 0; fm < 2; ++fm) {
        int n = n0 + wm * 32 + fm * 16 + lr;
        aoff[fm] = (size_t)((n < NROWS) ? n : (NROWS - 1)) * EE;
    }
    size_t boff[2];
    #pragma unroll
    for (int fn = 0; fn < 2; ++fn)
        boff[fn] = (size_t)(jp0 + wn * 32 + fn * 16 + lr) * 256;

    #pragma unroll
    for (int ks = 0; ks < 8; ++ks) {
        const ushort* src = (ks < 4) ? reg16 : hb16in;
        const int koff = ((ks < 4) ? ks : (ks - 4)) * 32 + lk;
        short8v a0 = *(const short8v*)(src + aoff[0] + koff);
        short8v a1 = *(const short8v*)(src + aoff[1] + koff);
        short8v b0 = *(const short8v*)(Wt + boff[0] + ks * 32 + lk);
        short8v b1 = *(const short8v*)(Wt + boff[1] + ks * 32 + lk);
        acc[0][0] = __builtin_amdgcn_mfma_f32_16x16x32_bf16(a0, b0, acc[0][0], 0, 0, 0);
        acc[0][1] = __builtin_amdgcn_mfma_f32_16x16x32_bf16(a0, b1, acc[0][1], 0, 0, 0);
        acc[1][0] = __builtin_amdgcn_mfma_f32_16x16x32_bf16(a1, b0, acc[1][0], 0, 0, 0);
        acc[1][1] = __builtin_amdgcn_mfma_f32_16x16x32_bf16(a1, b1, acc[1][1], 0, 0, 0);
    }

    #pragma unroll
    for (int fm = 0; fm < 2; ++fm)
        #pragma unroll
        for (int fn = 0; fn < 2; ++fn)
            #pragma unroll
            for (int r = 0; r < 4; ++r)
                gsm[wm * 32 + fm * 16 + (lane >> 4) * 4 + r]
                   [wn * 32 + fn * 16 + (lane & 15)] = acc[fm][fn][r];
    __syncthreads();

    const int jjl = tid & 15;
    const int jj = (jp0 >> 2) + jjl;
    const float4 bv = *(const float4*)(bc + jp0 + jjl * 4);
    #pragma unroll
    for (int i = 0; i < 4; ++i) {
        int nrel = (tid >> 4) * 4 + i;
        int n = n0 + nrel;
        float4 g = *(const float4*)&gsm[nrel][jjl * 4];
        float h2 = 0.f;
        if (n < NROWS) {
            float gi = g.x + bv.x, gf = g.y + bv.y, gg = g.z + bv.z, go = g.w + bv.w;
            size_t off = (size_t)n * EE + jj;
            float cv = cst[off];
            float c2 = sigf(gf) * cv + sigf(gi) * tanhf(gg);
            h2 = sigf(go) * tanhf(c2);
            cst[off] = c2;
            hb16out[off] = f2bf(h2);
        }
        h2sm[nrel][jjl] = h2;
    }
    __syncthreads();

    const int nrel2 = tid & 63;
    const int n2 = n0 + nrel2;
    if (n2 < NROWS) {
        const int b2 = n2 / PP, p2 = n2 - b2 * PP;
        const size_t base = MAPS_OFF + ((size_t)(b2 * NSTEP + t) * EE) * PP + p2;
        #pragma unroll
        for (int pass = 0; pass < 4; ++pass) {
            int jl = pass * 4 + (tid >> 6);
            out[base + (size_t)((jp0 >> 2) + jl) * PP] = h2sm[nrel2][jl];
        }
    }
}

// wprep: wT16[b][o][tap][e] = bf16( rot_o(img[b,t+1])[e][tap] )
__global__ __launch_bounds__(256) void k_wprep(const float* __restrict__ images,
                                               ushort* __restrict__ wT16, int t) {
    __shared__ float img_s[64][225];
    const int eh = blockIdx.x;
    const int o  = blockIdx.y;
    const int b  = blockIdx.z;
    const int tid = threadIdx.x;
    const float* img = images + ((size_t)(b * TT + t + 1) * EE + eh * 64) * 225;
    for (int i = tid; i < 64 * 225; i += 256)
        img_s[i / 225][i % 225] = img[i];
    __syncthreads();
    ushort* w = wT16 + ((size_t)(b * OO + o) * 225) * EE + eh * 64;
    for (int j = tid; j < 225 * 64; j += 256) {
        int tap = j >> 6, el = j & 63;
        int r = tap / 15, c = tap - r * 15;
        w[(size_t)tap * EE + el] = f2bf(img_s[el][rotoff(o, r, c)]);
    }
}

// localize v9 = v8 minus the two spill triggers: NO launch_bounds occupancy
// cap (the ",3" handed the allocator an 84-VGPR budget -> scratch), and the
// dyl loop NOT unrolled (full unroll kept multiple hrow[41] ranges live).
// Structure kept: dy-thirds in grid, 52.5 KB LDS slab -> 3 blocks/CU;
// 256 thr = 4 waves = o; lane = e-pair, packed dot2. rawp: [dyt=3][b][o][729].
__global__ __launch_bounds__(256) void k_localize(const ushort* __restrict__ h16,
                                                  const ushort* __restrict__ wT16,
                                                  float* __restrict__ rawp) {
    __shared__ ushort tile[5 * MM * EE];   // 52,480 B
    const int y   = blockIdx.x;            // 0..26
    const int b   = blockIdx.y;
    const int dyt = blockIdx.z;            // 0..2
    const int tid = threadIdx.x;
    const int o    = tid >> 6;             // wave = orientation
    const int lane = tid & 63;             // e-pair index
    const int dy0 = dyt * 5;

    // stage rows [y+dy0, y+dy0+5) x 128 e (contiguous, coalesced)
    const uint4* s4 = (const uint4*)(h16 + ((size_t)b * PP + (size_t)(y + dy0) * MM) * EE);
    uint4* d4 = (uint4*)tile;
    for (int i = tid; i < 3280; i += 256) d4[i] = s4[i];
    __syncthreads();

    float acc[SS];
    #pragma unroll
    for (int x = 0; x < SS; ++x) acc[x] = 0.f;

    const uint* tl = (const uint*)tile + lane;
    const uint* wo = (const uint*)(wT16 + (((size_t)b * OO + o) * 225) * EE) + lane;

    for (int dyl = 0; dyl < 5; ++dyl) {    // NOT unrolled (spill guard)
        uint hrow[MM];
        const uint* tr = tl + (size_t)dyl * MM * 64;
        #pragma unroll
        for (int c = 0; c < MM; ++c) hrow[c] = tr[c * 64];
        const uint* wd = wo + (size_t)((dy0 + dyl) * 15) * 64;
        #pragma unroll
        for (int dx = 0; dx < 15; ++dx) {
            uint uw = wd[dx * 64];
#if __has_builtin(__builtin_amdgcn_fdot2_f32_bf16)
            bf16x2 w2 = __builtin_bit_cast(bf16x2, uw);
            #pragma unroll
            for (int x = 0; x < SS; ++x)
                acc[x] = __builtin_amdgcn_fdot2_f32_bf16(
                    __builtin_bit_cast(bf16x2, hrow[x + dx]), w2, acc[x], false);
#else
            float wl = bf2f((ushort)(uw & 0xffffu));
            float wh = bf2f((ushort)(uw >> 16));
            #pragma unroll
            for (int x = 0; x < SS; ++x) {
                uint hu = hrow[x + dx];
                acc[x] += bf2f((ushort)(hu & 0xffffu)) * wl
                        + bf2f((ushort)(hu >> 16)) * wh;
            }
#endif
        }
    }

    #pragma unroll
    for (int x = 0; x < SS; ++x) {
        float v = acc[x];
        v += __shfl_xor(v, 1);  v += __shfl_xor(v, 2);  v += __shfl_xor(v, 4);
        v += __shfl_xor(v, 8);  v += __shfl_xor(v, 16); v += __shfl_xor(v, 32);
        if (lane == 0)
            rawp[(((size_t)dyt * BB + b) * OO + o) * (SS * SS) + y * SS + x] = v;
    }
}

__global__ __launch_bounds__(256) void k_softmax(const float* __restrict__ rawp,
                                                 float* __restrict__ out,
                                                 float* __restrict__ pose, int t) {
    const int b = blockIdx.x, tid = threadIdx.x;
    const int NTOT = OO * SS * SS;
    __shared__ float sv[OO * SS * SS];
    __shared__ float red[256];

    const float* p0 = rawp + (size_t)b * NTOT;
    for (int i = tid; i < NTOT; i += 256) {
        float s = 0.f;
        #pragma unroll
        for (int q = 0; q < NPS; ++q) s += p0[(size_t)q * BB * NTOT + i];
        sv[i] = s;
    }
    __syncthreads();

    float mx = -3.4e38f;
    for (int i = tid; i < NTOT; i += 256) mx = fmaxf(mx, sv[i]);
    red[tid] = mx; __syncthreads();
    for (int s = 128; s > 0; s >>= 1) {
        if (tid < s) red[tid] = fmaxf(red[tid], red[tid + s]);
        __syncthreads();
    }
    mx = red[0]; __syncthreads();

    float sm = 0.f;
    for (int i = tid; i < NTOT; i += 256) sm += expf(sv[i] - mx);
    red[tid] = sm; __syncthreads();
    for (int s = 128; s > 0; s >>= 1) {
        if (tid < s) red[tid] += red[tid + s];
        __syncthreads();
    }
    const float inv = 1.f / red[0];

    float* rawOut = out + RAWS_OFF + ((size_t)(b * NSTEP + t) * OO) * PP;
    float* spOut  = out + SPS_OFF  + ((size_t)(b * NSTEP + t) * OO) * PP;
    float* pb = pose + (size_t)b * OO * MM * MM;
    for (int i = tid; i < OO * MM * MM; i += 256) {
        int o = i / (MM * MM), rem = i % (MM * MM), yy = rem / MM - VR, xx = rem % MM - VR;
        float rv = 0.f, sv2 = 0.f;
        if ((unsigned)yy < SS && (unsigned)xx < SS) {
            float r = sv[(o * SS + yy) * SS + xx];
            rv = r;
            sv2 = expf(r - mx) * inv;
        }
        rawOut[i] = rv;
        spOut[i] = sv2;
        pb[i] = sv2;
    }
}

extern "C" void kernel_launch(void* const* d_in, const int* in_sizes, int n_in,
                              void* d_out, int out_size, void* d_ws, size_t ws_size,
                              hipStream_t stream) {
    const float* images = (const float*)d_in[0];
    const float* wih    = (const float*)d_in[1];
    const float* whh    = (const float*)d_in[2];
    const float* bih    = (const float*)d_in[3];
    const float* bhh    = (const float*)d_in[4];
    float* out = (float*)d_out;
    float* ws  = (float*)d_ws;

    // layout (float units), total ~10.5M floats = 42 MB
    float*  pose  = ws;                                   // 107,584
    float*  cst   = pose + 107584;                        // 3,442,688 fp32
    ushort* hbA   = (ushort*)(cst + 3442688);             // 1,721,344 float-slots
    ushort* hbB   = (ushort*)(cst + 3442688 + 1721344);   // 1,721,344 float-slots
    float*  regbF = cst + 3442688 + 2 * 1721344;          // 3,442,688 region
    ushort* reg16 = (ushort*)regbF;                       // bf16 reg
    // aliases inside regb region (dead between k_lstm(t) and k_register(t+1)):
    float*  rawp  = regbF;                                // 139,968 floats (NPS=3)
    ushort* wT16  = (ushort*)(regbF + 262144);            // 921,600 float-slots
    ushort* Wt    = (ushort*)(regbF + 3442688);           // 65,536 float-slots
    float*  bc    = regbF + 3442688 + 65536;              // 512

    hipMemsetAsync(hbA, 0, (size_t)1721344 * 4, stream);
    hipMemsetAsync(cst, 0, (size_t)3442688 * 4, stream);
    k_init<<<421, 256, 0, stream>>>(pose);
    k_prep<<<512, 256, 0, stream>>>(wih, whh, bih, bhh, Wt, bc);

    ushort* hbin = hbA;
    ushort* hbout = hbB;
    for (int t = 0; t < NSTEP; ++t) {
        k_register<<<dim3(7, 4, BB), 256, 0, stream>>>(images, pose, reg16, t);
        k_lstm<<<dim3(421, 8), 256, 0, stream>>>(reg16, hbin, Wt, bc, hbout, cst, out, t);
        k_wprep<<<dim3(2, OO, BB), 256, 0, stream>>>(images, wT16, t);
        k_localize<<<dim3(SS, BB, 3), 256, 0, stream>>>(hbout, wT16, rawp);
        k_softmax<<<BB, 256, 0, stream>>>(rawp, out, pose, t);
        ushort* tmp = hbin; hbin = hbout; hbout = tmp;
    }
}

// Round 16
// 2813.806 us; speedup vs baseline: 2.3887x; 1.0304x over previous
//
#include <hip/hip_runtime.h>
#include <math.h>

#define BB 16
#define TT 16
#define EE 128
#define KS 15
#define MM 41
#define OO 4
#define VR 7
#define SS 27
#define NSTEP 15
#define PP (MM*MM)
#define NROWS (BB*PP)

#define RAWS_OFF 0
#define SPS_OFF  1613760
#define MAPS_OFF 3227520

#define PM 55
#define PMSZ (PM*PM)
#define NPS 3

typedef __attribute__((ext_vector_type(8))) short short8v;
typedef __attribute__((ext_vector_type(4))) float f32x4;
typedef __attribute__((ext_vector_type(2))) __bf16 bf16x2;
typedef unsigned short ushort;
typedef unsigned int uint;

__device__ __forceinline__ float sigf(float x) { return 1.f / (1.f + expf(-x)); }

__device__ __forceinline__ ushort f2bf(float x) {
    unsigned int u = __float_as_uint(x);
    u += 0x7FFF + ((u >> 16) & 1);
    return (ushort)(u >> 16);
}
__device__ __forceinline__ float bf2f(ushort u) {
    return __uint_as_float((unsigned int)u << 16);
}

__device__ __forceinline__ int rotoff(int o, int r, int c) {
    int ir, ic;
    if (o == 0)      { ir = r;      ic = c;      }
    else if (o == 1) { ir = c;      ic = 14 - r; }
    else if (o == 2) { ir = 14 - r; ic = 14 - c; }
    else             { ir = 14 - c; ic = r;      }
    return ir * 15 + ic;
}

__global__ void k_init(float* __restrict__ pose) {
    int idx = blockIdx.x * 256 + threadIdx.x;
    if (idx < BB * OO * MM * MM) {
        int r = idx % (OO * MM * MM);
        pose[idx] = (r == (20 * MM + 20)) ? 1.f : 0.f;
    }
}

// Wt[jp][k] bf16 (B^T layout for MFMA), jp = jj*4+g; bc[jp] = bih+bhh
__global__ void k_prep(const float* __restrict__ wih, const float* __restrict__ whh,
                       const float* __restrict__ bih, const float* __restrict__ bhh,
                       ushort* __restrict__ Wt, float* __restrict__ bc) {
    int idx = blockIdx.x * 256 + threadIdx.x;   // [0, 512*256)
    int jp = idx >> 8, k = idx & 255;
    int jj = jp >> 2, g = jp & 3, j = g * 128 + jj;
    float v = (k < 128) ? wih[j * 128 + k] : whh[j * 128 + (k - 128)];
    Wt[(size_t)jp * 256 + k] = f2bf(v);
    if (idx < 512) {
        int jj2 = idx >> 2, g2 = idx & 3, j2 = g2 * 128 + jj2;
        bc[idx] = bih[j2] + bhh[j2];
    }
}

// register conv-transpose (R4-verified index math); bf16 output.
__global__ __launch_bounds__(256) void k_register(const float* __restrict__ images,
                                                  const float* __restrict__ pose,
                                                  ushort* __restrict__ reg16, int t) {
    __shared__ float ps[OO * PMSZ];
    __shared__ float wsm[225][36];
    const int p0 = blockIdx.x * 256;
    const int eq = blockIdx.y;
    const int b  = blockIdx.z;
    const int tid = threadIdx.x;

    for (int i = tid; i < OO * PMSZ; i += 256) {
        int o = i / PMSZ, rem = i % PMSZ, r = rem / PM, c = rem % PM;
        float v = 0.f;
        if (r >= VR && r < VR + MM && c >= VR && c < VR + MM)
            v = pose[(((size_t)b * OO + o) * MM + (r - VR)) * MM + (c - VR)];
        ps[i] = v;
    }
    const float* img = images + ((size_t)(b * TT + t) * EE + eq * 32) * 225;
    for (int i = tid; i < 32 * 225; i += 256) {
        int e = i / 225, k = i - e * 225;
        wsm[k][e] = img[e * 225 + k];
    }
    __syncthreads();

    const int px = tid & 63;
    const int ec = tid >> 6;
    int pbase[4];
    #pragma unroll
    for (int i = 0; i < 4; ++i) {
        int p = p0 + px + 64 * i;
        int pc = (p < PP) ? p : 0;
        int y = pc / MM, x = pc - y * MM;
        pbase[i] = (y + 2 * VR) * PM + (x + 2 * VR);
    }

    float acc[4][8];
    #pragma unroll
    for (int i = 0; i < 4; ++i)
        #pragma unroll
        for (int j = 0; j < 8; ++j) acc[i][j] = 0.f;

    for (int R = 0; R < 15; ++R) {
        #pragma unroll 5
        for (int C = 0; C < 15; ++C) {
            float4 wv0 = *(const float4*)&wsm[R * 15 + C][ec * 8];
            float4 wv1 = *(const float4*)&wsm[R * 15 + C][ec * 8 + 4];
            #pragma unroll
            for (int i = 0; i < 4; ++i) {
                float a0 = ps[0 * PMSZ + pbase[i] - R * PM - C];
                float a1 = ps[1 * PMSZ + pbase[i] + (C - 14) * PM - R];
                float a2 = ps[2 * PMSZ + pbase[i] + (R - 14) * PM + (C - 14)];
                float a3 = ps[3 * PMSZ + pbase[i] - C * PM + (R - 14)];
                float s = (a0 + a1) + (a2 + a3);
                acc[i][0] += s * wv0.x; acc[i][1] += s * wv0.y;
                acc[i][2] += s * wv0.z; acc[i][3] += s * wv0.w;
                acc[i][4] += s * wv1.x; acc[i][5] += s * wv1.y;
                acc[i][6] += s * wv1.z; acc[i][7] += s * wv1.w;
            }
        }
    }

    #pragma unroll
    for (int i = 0; i < 4; ++i) {
        int p = p0 + px + 64 * i;
        if (p < PP) {
            ushort* dst = reg16 + ((size_t)b * PP + p) * EE + eq * 32 + ec * 8;
            ushort u[8];
            #pragma unroll
            for (int j = 0; j < 8; ++j) u[j] = f2bf(acc[i][j]);
            *(uint4*)dst = *(uint4*)u;
        }
    }
}

// LSTM v2: 128n x 128jp block, 4 waves (2x2), each wave 64x64 = 4x4 frags of
// 16x16x32 MFMA. Arithmetic intensity 4x the old 64x64 tile (A+B L2 traffic
// 217 -> 82 MB/step). Epilogue in TWO jp-halves so LDS stays 43.5 KB
// (gsm 128x68 + h2sm 128x17) -> 3 blocks/CU. ks loop not unrolled (spill guard).
__global__ __launch_bounds__(256) void k_lstm(const ushort* __restrict__ reg16,
                                              const ushort* __restrict__ hb16in,
                                              const ushort* __restrict__ Wt,
                                              const float* __restrict__ bc,
                                              ushort* __restrict__ hb16out,
                                              float* __restrict__ cst,
                                              float* __restrict__ out, int t) {
    __shared__ float gsm[128][68];    // one 64-jp half, +4 pad
    __shared__ float h2sm[128][17];   // 16 jj of the half, +1 pad
    const int tid = threadIdx.x;
    const int wave = tid >> 6, lane = tid & 63;
    const int wm = wave >> 1, wn = wave & 1;
    const int n0 = blockIdx.x * 128;
    const int jp0 = blockIdx.y * 128;
    const int lr = lane & 15;
    const int lk = (lane >> 4) * 8;

    f32x4 acc[4][4];
    #pragma unroll
    for (int fm = 0; fm < 4; ++fm)
        #pragma unroll
        for (int fn = 0; fn < 4; ++fn) acc[fm][fn] = (f32x4){0.f, 0.f, 0.f, 0.f};

    size_t aoff[4];
    #pragma unroll
    for (int fm = 0; fm < 4; ++fm) {
        int n = n0 + wm * 64 + fm * 16 + lr;
        aoff[fm] = (size_t)((n < NROWS) ? n : (NROWS - 1)) * EE;
    }
    size_t boff[4];
    #pragma unroll
    for (int fn = 0; fn < 4; ++fn)
        boff[fn] = (size_t)(jp0 + wn * 64 + fn * 16 + lr) * 256;

    for (int ks = 0; ks < 8; ++ks) {     // not unrolled (VGPR guard)
        const ushort* src = (ks < 4) ? reg16 : hb16in;
        const int koff = ((ks < 4) ? ks : (ks - 4)) * 32 + lk;
        short8v a[4], bv[4];
        #pragma unroll
        for (int fm = 0; fm < 4; ++fm) a[fm] = *(const short8v*)(src + aoff[fm] + koff);
        #pragma unroll
        for (int fn = 0; fn < 4; ++fn) bv[fn] = *(const short8v*)(Wt + boff[fn] + ks * 32 + lk);
        #pragma unroll
        for (int fm = 0; fm < 4; ++fm)
            #pragma unroll
            for (int fn = 0; fn < 4; ++fn)
                acc[fm][fn] = __builtin_amdgcn_mfma_f32_16x16x32_bf16(a[fm], bv[fn], acc[fm][fn], 0, 0, 0);
    }

    #pragma unroll
    for (int half = 0; half < 2; ++half) {
        // waves owning this jp-half stage their gates to LDS
        if (wn == half) {
            #pragma unroll
            for (int fm = 0; fm < 4; ++fm)
                #pragma unroll
                for (int fn = 0; fn < 4; ++fn)
                    #pragma unroll
                    for (int r = 0; r < 4; ++r)
                        gsm[wm * 64 + fm * 16 + (lane >> 4) * 4 + r]
                           [fn * 16 + (lane & 15)] = acc[fm][fn][r];
        }
        __syncthreads();

        const int jph0 = jp0 + half * 64;
        const int jjl = tid & 15;             // 16 jj in this half
        const int jj = (jph0 >> 2) + jjl;
        const float4 bvv = *(const float4*)(bc + jph0 + jjl * 4);
        for (int i = 0; i < 8; ++i) {
            int nrel = (tid >> 4) * 8 + i;
            int n = n0 + nrel;
            float4 g = *(const float4*)&gsm[nrel][jjl * 4];
            float h2 = 0.f;
            if (n < NROWS) {
                float gi = g.x + bvv.x, gf = g.y + bvv.y, gg = g.z + bvv.z, go = g.w + bvv.w;
                size_t off = (size_t)n * EE + jj;
                float cv = cst[off];
                float c2 = sigf(gf) * cv + sigf(gi) * tanhf(gg);
                h2 = sigf(go) * tanhf(c2);
                cst[off] = c2;
                hb16out[off] = f2bf(h2);
            }
            h2sm[nrel][jjl] = h2;
        }
        __syncthreads();

        // fused maps write for this half (16 jj), coalesced over n
        const int nrel2 = tid & 127;
        const int n2 = n0 + nrel2;
        if (n2 < NROWS) {
            const int b2 = n2 / PP, p2 = n2 - b2 * PP;
            const size_t base = MAPS_OFF + ((size_t)(b2 * NSTEP + t) * EE) * PP + p2;
            #pragma unroll
            for (int pass = 0; pass < 8; ++pass) {
                int jl = pass * 2 + (tid >> 7);
                out[base + (size_t)((jph0 >> 2) + jl) * PP] = h2sm[nrel2][jl];
            }
        }
        __syncthreads();   // protect gsm/h2sm before next half
    }
}

// wprep: wT16[b][o][tap][e] = bf16( rot_o(img[b,t+1])[e][tap] )
__global__ __launch_bounds__(256) void k_wprep(const float* __restrict__ images,
                                               ushort* __restrict__ wT16, int t) {
    __shared__ float img_s[64][225];
    const int eh = blockIdx.x;
    const int o  = blockIdx.y;
    const int b  = blockIdx.z;
    const int tid = threadIdx.x;
    const float* img = images + ((size_t)(b * TT + t + 1) * EE + eh * 64) * 225;
    for (int i = tid; i < 64 * 225; i += 256)
        img_s[i / 225][i % 225] = img[i];
    __syncthreads();
    ushort* w = wT16 + ((size_t)(b * OO + o) * 225) * EE + eh * 64;
    for (int j = tid; j < 225 * 64; j += 256) {
        int tap = j >> 6, el = j & 63;
        int r = tap / 15, c = tap - r * 15;
        w[(size_t)tap * EE + el] = f2bf(img_s[el][rotoff(o, r, c)]);
    }
}

// localize v9 (R15-proven): dy-thirds in grid, 52.5 KB LDS slab, 3 blocks/CU;
// 256 thr = 4 waves = o; lane = e-pair, packed dot2; no launch_bounds cap,
// dyl loop not unrolled. rawp: [dyt=3][b][o][729].
__global__ __launch_bounds__(256) void k_localize(const ushort* __restrict__ h16,
                                                  const ushort* __restrict__ wT16,
                                                  float* __restrict__ rawp) {
    __shared__ ushort tile[5 * MM * EE];   // 52,480 B
    const int y   = blockIdx.x;            // 0..26
    const int b   = blockIdx.y;
    const int dyt = blockIdx.z;            // 0..2
    const int tid = threadIdx.x;
    const int o    = tid >> 6;             // wave = orientation
    const int lane = tid & 63;             // e-pair index
    const int dy0 = dyt * 5;

    const uint4* s4 = (const uint4*)(h16 + ((size_t)b * PP + (size_t)(y + dy0) * MM) * EE);
    uint4* d4 = (uint4*)tile;
    for (int i = tid; i < 3280; i += 256) d4[i] = s4[i];
    __syncthreads();

    float acc[SS];
    #pragma unroll
    for (int x = 0; x < SS; ++x) acc[x] = 0.f;

    const uint* tl = (const uint*)tile + lane;
    const uint* wo = (const uint*)(wT16 + (((size_t)b * OO + o) * 225) * EE) + lane;

    for (int dyl = 0; dyl < 5; ++dyl) {    // NOT unrolled (spill guard)
        uint hrow[MM];
        const uint* tr = tl + (size_t)dyl * MM * 64;
        #pragma unroll
        for (int c = 0; c < MM; ++c) hrow[c] = tr[c * 64];
        const uint* wd = wo + (size_t)((dy0 + dyl) * 15) * 64;
        #pragma unroll
        for (int dx = 0; dx < 15; ++dx) {
            uint uw = wd[dx * 64];
#if __has_builtin(__builtin_amdgcn_fdot2_f32_bf16)
            bf16x2 w2 = __builtin_bit_cast(bf16x2, uw);
            #pragma unroll
            for (int x = 0; x < SS; ++x)
                acc[x] = __builtin_amdgcn_fdot2_f32_bf16(
                    __builtin_bit_cast(bf16x2, hrow[x + dx]), w2, acc[x], false);
#else
            float wl = bf2f((ushort)(uw & 0xffffu));
            float wh = bf2f((ushort)(uw >> 16));
            #pragma unroll
            for (int x = 0; x < SS; ++x) {
                uint hu = hrow[x + dx];
                acc[x] += bf2f((ushort)(hu & 0xffffu)) * wl
                        + bf2f((ushort)(hu >> 16)) * wh;
            }
#endif
        }
    }

    #pragma unroll
    for (int x = 0; x < SS; ++x) {
        float v = acc[x];
        v += __shfl_xor(v, 1);  v += __shfl_xor(v, 2);  v += __shfl_xor(v, 4);
        v += __shfl_xor(v, 8);  v += __shfl_xor(v, 16); v += __shfl_xor(v, 32);
        if (lane == 0)
            rawp[(((size_t)dyt * BB + b) * OO + o) * (SS * SS) + y * SS + x] = v;
    }
}

__global__ __launch_bounds__(256) void k_softmax(const float* __restrict__ rawp,
                                                 float* __restrict__ out,
                                                 float* __restrict__ pose, int t) {
    const int b = blockIdx.x, tid = threadIdx.x;
    const int NTOT = OO * SS * SS;
    __shared__ float sv[OO * SS * SS];
    __shared__ float red[256];

    const float* p0 = rawp + (size_t)b * NTOT;
    for (int i = tid; i < NTOT; i += 256) {
        float s = 0.f;
        #pragma unroll
        for (int q = 0; q < NPS; ++q) s += p0[(size_t)q * BB * NTOT + i];
        sv[i] = s;
    }
    __syncthreads();

    float mx = -3.4e38f;
    for (int i = tid; i < NTOT; i += 256) mx = fmaxf(mx, sv[i]);
    red[tid] = mx; __syncthreads();
    for (int s = 128; s > 0; s >>= 1) {
        if (tid < s) red[tid] = fmaxf(red[tid], red[tid + s]);
        __syncthreads();
    }
    mx = red[0]; __syncthreads();

    float sm = 0.f;
    for (int i = tid; i < NTOT; i += 256) sm += expf(sv[i] - mx);
    red[tid] = sm; __syncthreads();
    for (int s = 128; s > 0; s >>= 1) {
        if (tid < s) red[tid] += red[tid + s];
        __syncthreads();
    }
    const float inv = 1.f / red[0];

    float* rawOut = out + RAWS_OFF + ((size_t)(b * NSTEP + t) * OO) * PP;
    float* spOut  = out + SPS_OFF  + ((size_t)(b * NSTEP + t) * OO) * PP;
    float* pb = pose + (size_t)b * OO * MM * MM;
    for (int i = tid; i < OO * MM * MM; i += 256) {
        int o = i / (MM * MM), rem = i % (MM * MM), yy = rem / MM - VR, xx = rem % MM - VR;
        float rv = 0.f, sv2 = 0.f;
        if ((unsigned)yy < SS && (unsigned)xx < SS) {
            float r = sv[(o * SS + yy) * SS + xx];
            rv = r;
            sv2 = expf(r - mx) * inv;
        }
        rawOut[i] = rv;
        spOut[i] = sv2;
        pb[i] = sv2;
    }
}

extern "C" void kernel_launch(void* const* d_in, const int* in_sizes, int n_in,
                              void* d_out, int out_size, void* d_ws, size_t ws_size,
                              hipStream_t stream) {
    const float* images = (const float*)d_in[0];
    const float* wih    = (const float*)d_in[1];
    const float* whh    = (const float*)d_in[2];
    const float* bih    = (const float*)d_in[3];
    const float* bhh    = (const float*)d_in[4];
    float* out = (float*)d_out;
    float* ws  = (float*)d_ws;

    // layout (float units), total ~10.5M floats = 42 MB
    float*  pose  = ws;                                   // 107,584
    float*  cst   = pose + 107584;                        // 3,442,688 fp32
    ushort* hbA   = (ushort*)(cst + 3442688);             // 1,721,344 float-slots
    ushort* hbB   = (ushort*)(cst + 3442688 + 1721344);   // 1,721,344 float-slots
    float*  regbF = cst + 3442688 + 2 * 1721344;          // 3,442,688 region
    ushort* reg16 = (ushort*)regbF;                       // bf16 reg
    // aliases inside regb region (dead between k_lstm(t) and k_register(t+1)):
    float*  rawp  = regbF;                                // 139,968 floats (NPS=3)
    ushort* wT16  = (ushort*)(regbF + 262144);            // 921,600 float-slots
    ushort* Wt    = (ushort*)(regbF + 3442688);           // 65,536 float-slots
    float*  bc    = regbF + 3442688 + 65536;              // 512

    hipMemsetAsync(hbA, 0, (size_t)1721344 * 4, stream);
    hipMemsetAsync(cst, 0, (size_t)3442688 * 4, stream);
    k_init<<<421, 256, 0, stream>>>(pose);
    k_prep<<<512, 256, 0, stream>>>(wih, whh, bih, bhh, Wt, bc);

    ushort* hbin = hbA;
    ushort* hbout = hbB;
    for (int t = 0; t < NSTEP; ++t) {
        k_register<<<dim3(7, 4, BB), 256, 0, stream>>>(images, pose, reg16, t);
        k_lstm<<<dim3(211, 4), 256, 0, stream>>>(reg16, hbin, Wt, bc, hbout, cst, out, t);
        k_wprep<<<dim3(2, OO, BB), 256, 0, stream>>>(images, wT16, t);
        k_localize<<<dim3(SS, BB, 3), 256, 0, stream>>>(hbout, wT16, rawp);
        k_softmax<<<BB, 256, 0, stream>>>(rawp, out, pose, t);
        ushort* tmp = hbin; hbin = hbout; hbout = tmp;
    }
}